// Round 16
// baseline (4132.288 us; speedup 1.0000x reference)
//
#include <hip/hip_runtime.h>

typedef _Float16 f16;
typedef _Float16 f16x8 __attribute__((ext_vector_type(8)));
typedef float f32x4 __attribute__((ext_vector_type(4)));
typedef float f32x2 __attribute__((ext_vector_type(2)));
typedef unsigned long long u64;

#define DEVFN static __device__ __forceinline__

#define NBLK 256

// ---------------- workspace layout (bytes) ----------------
#define OFF_WCAT 0ULL                          // 2048*768*2 gates weights
#define OFF_WT1A (OFF_WCAT + 2048ULL*768*2)    // 512*512*2  (W1h + W1m/5)
#define OFF_WT1B (OFF_WT1A + 512ULL*512*2)     // 512*512*2  (W1m/5)
#define OFF_HB0  (OFF_WT1B + 512ULL*512*2)     // 256*512*2  h_new parity 0
#define OFF_HB1  (OFF_HB0  + 256ULL*512*2)     // 256*512*2  h_new parity 1
#define OFF_BSUM (OFF_HB1  + 256ULL*512*2)     // 2048*4
#define OFF_U    (OFF_BSUM + 2048ULL*4)
#define OFF_V    (OFF_U    + 512ULL*256*4)
#define OFF_CU   (OFF_V    + 512ULL*256*4)
#define OFF_CV   (OFF_CU   + 512ULL*4)
#define OFF_ZETA (OFF_CV   + 512ULL*4)
#define OFF_RES  (OFF_ZETA + 512ULL*4)         // 512*256*4
#define OFF_TENSP (OFF_RES + 512ULL*256*4)     // 2 par * 8 panel * 32 q * 32 b * 4B = 64KB
#define OFF_SLOT (OFF_TENSP + 16384ULL*4)      // 8 panels * 128 u32 (per-wave sub-slots)

__constant__ float CGAM[15] = {14.134725f, 21.02204f, 25.010858f, 30.424876f, 32.935062f,
  37.586178f, 40.91872f, 43.327073f, 48.005151f, 49.773832f, 52.970321f,
  56.446248f, 59.347044f, 60.831779f, 65.112544f};

DEVFN float sigf(float v) { return 1.f / (1.f + __expf(-v)); }
DEVFN float tanh_(float v) {
  v = fminf(fmaxf(v, -15.f), 15.f);
  float e = __expf(2.f * v);
  return (e - 1.f) / (e + 1.f);
}

// ---- fence-free LLC-coherent access helpers ----
DEVFN float ald_f32(const float* p) {
  unsigned v = __hip_atomic_load((const unsigned*)p, __ATOMIC_RELAXED, __HIP_MEMORY_SCOPE_AGENT);
  union { unsigned u; float f; } c; c.u = v; return c.f;
}
DEVFN void ast_f32(float* p, float v) {
  union { float f; unsigned u; } c; c.f = v;
  __hip_atomic_store((unsigned*)p, c.u, __ATOMIC_RELAXED, __HIP_MEMORY_SCOPE_AGENT);
}
DEVFN u64 ald_u64(const void* p) {
  return __hip_atomic_load((const u64*)p, __ATOMIC_RELAXED, __HIP_MEMORY_SCOPE_AGENT);
}
DEVFN void ast_u32(void* p, unsigned v) {
  __hip_atomic_store((unsigned*)p, v, __ATOMIC_RELAXED, __HIP_MEMORY_SCOPE_AGENT);
}
DEVFN unsigned ald_u32(const void* p) {
  return __hip_atomic_load((const unsigned*)p, __ATOMIC_RELAXED, __HIP_MEMORY_SCOPE_AGENT);
}

// per-wave producer post: wave-local vmem drain + lane0 sub-slot store (NO block barrier)
DEVFN void post_wave(unsigned* subslot, unsigned v, int lane) {
  asm volatile("s_waitcnt vmcnt(0)" ::: "memory");
  if (lane == 0)
    __hip_atomic_store(subslot, v, __ATOMIC_RELAXED, __HIP_MEMORY_SCOPE_AGENT);
}
// consumer: poll 128 sub-slots (2 u32 per lane) until all >= target
DEVFN void poll_line128(const unsigned* base, unsigned target, int lane) {
  const unsigned* p0 = base + lane;
  const unsigned* p1 = base + 64 + lane;
  long sp = 0;
  for (;;) {
    unsigned v0 = ald_u32(p0), v1 = ald_u32(p1);
    if (__all((v0 >= target) & (v1 >= target))) break;
    __builtin_amdgcn_s_sleep(1);
    if (++sp > (1L << 21)) break;
  }
}

// ---------------- init ----------------
__global__ void k_init(const float* __restrict__ x, const float* __restrict__ Wih,
                       const float* __restrict__ Whh, const float* __restrict__ bih,
                       const float* __restrict__ bhh, const float* __restrict__ Wt1f,
                       char* __restrict__ ws) {
  f16* Wcat = (f16*)(ws + OFF_WCAT);
  f16* WhmA = (f16*)(ws + OFF_WT1A);
  f16* WmB  = (f16*)(ws + OFF_WT1B);
  f16* hb0  = (f16*)(ws + OFF_HB0);
  float* bsum = (float*)(ws + OFF_BSUM);
  float* tensP = (float*)(ws + OFF_TENSP);
  unsigned* slots = (unsigned*)(ws + OFF_SLOT);
  int gtid = blockIdx.x * blockDim.x + threadIdx.x;
  int nth = gridDim.x * blockDim.x;
  for (int i = gtid; i < 2048 * 768; i += nth) {
    int n = i / 768, k = i - n * 768;
    float w = (k < 256) ? Wih[n * 256 + k] : Whh[n * 512 + (k - 256)];
    Wcat[i] = (f16)w;
  }
  for (int i = gtid; i < 512 * 512; i += nth) {
    int n = i >> 9, k = i & 511;
    float wh = Wt1f[n * 1024 + k];
    float wm = Wt1f[n * 1024 + 512 + k] * 0.2f;
    WhmA[i] = (f16)(wh + wm);
    WmB[i]  = (f16)wm;
  }
  for (int i = gtid; i < 2048; i += nth) bsum[i] = bih[i] + bhh[i];
  for (int i = gtid; i < 256 * 512; i += nth) hb0[i] = (f16)0.f;
  for (int i = gtid; i < 16384; i += nth) tensP[i] = 0.f;
  for (int i = gtid; i < 8 * 128; i += nth) slots[i] = 0u;
}

// ---------------- per-t tables ----------------
__global__ void k_tables(const float* __restrict__ Wproj, const float* __restrict__ bproj,
                         char* __restrict__ ws) {
  float* u    = (float*)(ws + OFF_U);
  float* v    = (float*)(ws + OFF_V);
  float* cu   = (float*)(ws + OFF_CU);
  float* cv   = (float*)(ws + OFF_CV);
  float* zeta = (float*)(ws + OFF_ZETA);
  int t = blockIdx.x;
  int k = threadIdx.x;
  float tf = (float)t;
  float cg[15], sg[15], ph[15];
  #pragma unroll
  for (int m = 0; m < 15; ++m) {
    float ang = CGAM[m] * tf;
    cg[m] = cosf(ang);
    sg[m] = sinf(ang);
    ph[m] = (float)exp(-0.1 * (double)CGAM[m]);
  }
  float uu = 0.f, vv = 0.f;
  #pragma unroll
  for (int m = 0; m < 15; ++m) {
    uu += Wproj[m * 256 + k] * cg[m] * ph[m];
    vv += Wproj[(15 + m) * 256 + k] * sg[m] * ph[m];
  }
  u[t * 256 + k] = uu;
  v[t * 256 + k] = vv;
  if (k == 0) {
    float a = 0.f, b2 = 0.f, z = 0.f;
    #pragma unroll
    for (int m = 0; m < 15; ++m) {
      a  += bproj[m] * cg[m] * ph[m];
      b2 += bproj[15 + m] * sg[m] * ph[m];
      z  += ph[m] * cg[m];
    }
    cu[t] = a; cv[t] = b2; zeta[t] = z / 15.f;
  }
}

// ---------------- resonance precompute ----------------
__global__ void k_res(const float* __restrict__ x, char* __restrict__ ws) {
  const float* u  = (const float*)(ws + OFF_U);
  const float* v  = (const float*)(ws + OFF_V);
  const float* cu = (const float*)(ws + OFF_CU);
  const float* cv = (const float*)(ws + OFF_CV);
  float* resb     = (float*)(ws + OFF_RES);
  int wid = blockIdx.x * 4 + (threadIdx.x >> 6);
  int l = threadIdx.x & 63;
  int b = wid >> 9, t = wid & 511;
  const f32x4 xx = *(const f32x4*)(x + ((size_t)(b * 512 + t)) * 256 + l * 4);
  const f32x4 uu = *(const f32x4*)(u + t * 256 + l * 4);
  const f32x4 vv = *(const f32x4*)(v + t * 256 + l * 4);
  float cc = xx[0]*uu[0] + xx[1]*uu[1] + xx[2]*uu[2] + xx[3]*uu[3];
  float ss = xx[0]*vv[0] + xx[1]*vv[1] + xx[2]*vv[2] + xx[3]*vv[3];
  #pragma unroll
  for (int m = 1; m < 64; m <<= 1) { cc += __shfl_xor(cc, m); ss += __shfl_xor(ss, m); }
  if (l == 0) {
    cc += cu[t]; ss += cv[t];
    float r = sqrtf(cc * cc + ss * ss + 1e-8f) - 0.5f;
    resb[t * 256 + b] = sigf(r);
  }
}

#define MFMA16(qv, wv, av) av = __builtin_amdgcn_mfma_f32_16x16x32_f16(qv, wv, av, 0, 0, 0)

// ---------------- persistent fused recurrent kernel (256 blocks, uniform) ----------------
// Fragment-recurrence one-hop schedule (R12/R15) + per-wave sub-slot posting (no block
// barrier in post) + speculative slot check (detect read absorbed under slack MFMA).
__global__ void __launch_bounds__(256, 1)
k_lstm(const float* __restrict__ x, const float* __restrict__ bt1,
       const float* __restrict__ wt2, const float* __restrict__ bt2,
       const float* __restrict__ wg, const float* __restrict__ bg,
       float* __restrict__ out, char* __restrict__ ws) {
  extern __shared__ char lds[];
  char*  sH   = lds;                        // 32 KB  h_new tile [32][512] f16 swizzled
  char*  sXt0 = lds + 32768;                // 16 KB  x tile buf0
  char*  sXt1 = lds + 49152;                // 16 KB  x tile buf1
  float* sT   = (float*)(lds + 65536);      // 9216 B tension exchange [4][64][9]
  float* sX   = (float*)(lds + 74752);      // 10 KB  gate exchange [4][32][20] f32
  float* sGZ  = (float*)(lds + 84992);      // 256 B  gz parity-double [2][32]

  const f16* __restrict__ Wcat = (const f16*)(ws + OFF_WCAT);
  const f16* __restrict__ WhmA = (const f16*)(ws + OFF_WT1A);
  const f16* __restrict__ WmB  = (const f16*)(ws + OFF_WT1B);
  f16* hb[2] = { (f16*)(ws + OFF_HB0), (f16*)(ws + OFF_HB1) };
  const float* bsum = (const float*)(ws + OFF_BSUM);
  const float* zeta = (const float*)(ws + OFF_ZETA);
  const float* resb = (const float*)(ws + OFF_RES);
  float* tensP = (float*)(ws + OFF_TENSP);
  unsigned* slots = (unsigned*)(ws + OFF_SLOT);

  const int tid = threadIdx.x;
  const int w = tid >> 6, l = tid & 63;
  const int r0 = l & 15, kq = l >> 4;
  const int bid = blockIdx.x;
  const int p = bid >> 5, q = bid & 31;
  const int c0 = q * 16, m0 = p * 32;

  unsigned* slotB = slots + p * 128;        // 128 sub-slots (32 blocks x 4 waves)
  unsigned* mySlot = slotB + q * 4 + w;

  // ---- persistent weight fragments (registers) ----
  f16x8 wbh[16], wbx[8];
  {
    const f16* Wr = Wcat + (size_t)(w * 512 + c0 + r0) * 768 + kq * 8;
    #pragma unroll
    for (int ks = 0; ks < 16; ++ks) wbh[ks] = *(const f16x8*)(Wr + 256 + ks * 32);
    #pragma unroll
    for (int ks = 0; ks < 8; ++ks)  wbx[ks] = *(const f16x8*)(Wr + ks * 32);
  }
  f16x8 wbhm[4], wbm[4];   // tension weights, K-split: wave w owns k in [w*128, w*128+128)
  {
    const f16* Wa = WhmA + (size_t)(q * 16 + r0) * 512 + w * 128 + kq * 8;
    const f16* Wb = WmB  + (size_t)(q * 16 + r0) * 512 + w * 128 + kq * 8;
    #pragma unroll
    for (int ks = 0; ks < 4; ++ks) {
      wbhm[ks] = *(const f16x8*)(Wa + ks * 32);
      wbm[ks]  = *(const f16x8*)(Wb + ks * 32);
    }
  }
  const float b1a = bt1[q * 16 + r0], w2a = wt2[q * 16 + r0];

  // ---- per-thread pointwise state: batch b_loc, cols c0+c_loc, +1 ----
  const int b_loc = tid >> 3, c_loc = (tid & 7) * 2;
  const int pb = m0 + b_loc;
  float bsv[4][2];
  #pragma unroll
  for (int g = 0; g < 4; ++g) {
    bsv[g][0] = bsum[g * 512 + c0 + c_loc];
    bsv[g][1] = bsum[g * 512 + c0 + c_loc + 1];
  }
  const float wg0 = wg[0], wg1 = wg[1], bt2v = bt2[0], bgv = bg[0];
  float cst[2] = {0.f, 0.f};       // c_t
  float hst[2] = {0.f, 0.f};       // h^out_{t-2}
  float hnp[2] = {0.f, 0.f};       // h_new_{t-1}

  // fragment recurrences
  f32x4 gho0 = {0,0,0,0}, gho1 = {0,0,0,0};   // Wh@h^out_{t-1}
  f32x4 t1o0 = {0,0,0,0}, t1o1 = {0,0,0,0};   // Whm@h^out_{t-1} (K-slice)
  f32x4 R[4][2];                               // C^out ring
  #pragma unroll
  for (int s = 0; s < 4; ++s) { R[s][0] = (f32x4){0,0,0,0}; R[s][1] = (f32x4){0,0,0,0}; }

  // ---- prologue: stage x_0 -> sXt0, PGx(0); stage x_1 -> sXt1 ----
  f32x4 ppx0 = {0,0,0,0}, ppx1 = {0,0,0,0};
  {
    #pragma unroll
    for (int i = 0; i < 4; ++i) {
      const int U = i * 256 + tid;
      const int row = U >> 5, c = U & 31;
      const float* xp = x + ((size_t)(m0 + row) * 512 + 0) * 256 + c * 8;
      f32x4 xa = *(const f32x4*)xp;
      f32x4 xb_ = *(const f32x4*)(xp + 4);
      f16x8 xf;
      #pragma unroll
      for (int r = 0; r < 4; ++r) { xf[r] = (f16)xa[r]; xf[4 + r] = (f16)xb_[r]; }
      *(f16x8*)(sXt0 + row * 512 + ((c ^ (row & 7)) << 4)) = xf;
    }
    __syncthreads();
    #pragma unroll
    for (int ks = 0; ks < 8; ++ks) {
      const int cc = (((ks * 4 + kq) ^ (r0 & 7)) << 4);
      f16x8 a0 = *(const f16x8*)(sXt0 + r0 * 512 + cc);
      f16x8 a1 = *(const f16x8*)(sXt0 + (r0 + 16) * 512 + cc);
      MFMA16(a0, wbx[ks], ppx0); MFMA16(a1, wbx[ks], ppx1);
    }
    #pragma unroll
    for (int i = 0; i < 4; ++i) {
      const int U = i * 256 + tid;
      const int row = U >> 5, c = U & 31;
      const float* xp = x + ((size_t)(m0 + row) * 512 + 1) * 256 + c * 8;
      f32x4 xa = *(const f32x4*)xp;
      f32x4 xb_ = *(const f32x4*)(xp + 4);
      f16x8 xf;
      #pragma unroll
      for (int r = 0; r < 4; ++r) { xf[r] = (f16)xa[r]; xf[4 + r] = (f16)xb_[r]; }
      *(f16x8*)(sXt1 + row * 512 + ((c ^ (row & 7)) << 4)) = xf;
    }
    __syncthreads();
  }

  unsigned spec0 = 0u, spec1 = 0u;   // speculative slot words from previous slack

  for (int t = 0; t < 512; ++t) {
    const int par = t & 1, parm = (t - 1) & 1;

    // ---- detect: use speculative values if satisfied, else poll ----
    if (!__all((spec0 >= (unsigned)t) & (spec1 >= (unsigned)t)))
      poll_line128(slotB, (unsigned)t, l);

    // ---- issue h stage loads FIRST (latency overlaps gz compute below) ----
    u64 lo[8], hi[8];
    if (t > 0) {
      const f16* hsrc = hb[parm];
      #pragma unroll
      for (int i = 0; i < 8; ++i) {
        const int B = i * 256 + tid;
        const int row = B >> 6, c = B & 63;
        const u64* pp = (const u64*)(hsrc + (size_t)(m0 + row) * 512 + c * 8);
        lo[i] = ald_u64(pp); hi[i] = ald_u64(pp + 1);
      }
    }

    // ---- gz_{t-1} (VALU + 4 LLC reads, overlapped with the loads above) ----
    {
      float tn = 0.f;
      if (t >= 3) {
        const float* tpb = tensP + ((size_t)parm * 8 + p) * 1024;   // [q][32]
        const int s8 = tid & 7;
        float acc = 0.f;
        #pragma unroll
        for (int j2 = 0; j2 < 4; ++j2)
          acc += ald_f32(tpb + (s8 * 4 + j2) * 32 + b_loc);
        acc += __shfl_xor(acc, 1); acc += __shfl_xor(acc, 2); acc += __shfl_xor(acc, 4);
        tn = sigf(acc + bt2v);
      }
      float g = 0.f;
      if (t >= 1) {
        float rs = resb[(t - 1) * 256 + pb];
        g = sigf(wg0 * rs + wg1 * tn + bgv) * zeta[t - 1];
      }
      if ((tid & 7) == 0) sGZ[par * 32 + b_loc] = g;
    }

    // ---- LDS writes of the staged h tile ----
    if (t > 0) {
      #pragma unroll
      for (int i = 0; i < 8; ++i) {
        const int B = i * 256 + tid;
        const int row = B >> 6, c = B & 63;
        union { u64 qq[2]; uint4 v4; } uq; uq.qq[0] = lo[i]; uq.qq[1] = hi[i];
        *(uint4*)(sH + row * 1024 + ((c ^ (row & 7)) << 4)) = uq.v4;
      }
    }
    __syncthreads();

    // ---- GEMMs on h_new_{t-1} ----
    f32x4 ghn0 = {0,0,0,0}, ghn1 = {0,0,0,0};
    f32x4 t1n0 = {0,0,0,0}, t1n1 = {0,0,0,0};
    f32x4 cnw0 = {0,0,0,0}, cnw1 = {0,0,0,0};
    if (t > 0) {
      #pragma unroll
      for (int ks = 0; ks < 16; ++ks) {
        const int cc = (((ks * 4 + kq) ^ (r0 & 7)) << 4);
        f16x8 q0 = *(const f16x8*)(sH + r0 * 1024 + cc);
        f16x8 q1 = *(const f16x8*)(sH + (r0 + 16) * 1024 + cc);
        MFMA16(q0, wbh[ks], ghn0); MFMA16(q1, wbh[ks], ghn1);
      }
      #pragma unroll
      for (int ks = 0; ks < 4; ++ks) {
        const int cc = ((((w * 4 + ks) * 4 + kq) ^ (r0 & 7)) << 4);
        f16x8 q0 = *(const f16x8*)(sH + r0 * 1024 + cc);
        f16x8 q1 = *(const f16x8*)(sH + (r0 + 16) * 1024 + cc);
        MFMA16(q0, wbhm[ks], t1n0); MFMA16(q1, wbhm[ks], t1n1);
        MFMA16(q0, wbm[ks],  cnw0); MFMA16(q1, wbm[ks],  cnw1);
      }
    }

    // ---- fragment recurrences (gz_{t-1} from sGZ) + exchanges ----
    {
      float gz0[4], gz1[4];
      #pragma unroll
      for (int r = 0; r < 4; ++r) {
        gz0[r] = sGZ[par * 32 + kq * 4 + r];
        gz1[r] = sGZ[par * 32 + 16 + kq * 4 + r];
      }
      f32x4 co0, co1, tp0, tp1;
      #pragma unroll
      for (int r = 0; r < 4; ++r) {
        gho0[r] = ghn0[r] + gz0[r] * gho0[r];
        gho1[r] = ghn1[r] + gz1[r] * gho1[r];
        t1o0[r] = t1n0[r] + gz0[r] * t1o0[r];
        t1o1[r] = t1n1[r] + gz1[r] * t1o1[r];
        co0[r] = cnw0[r] + gz0[r] * R[0][0][r];
        co1[r] = cnw1[r] + gz1[r] * R[0][1][r];
        tp0[r] = t1o0[r] + R[0][0][r] + R[1][0][r] + R[2][0][r] + R[3][0][r];
        tp1[r] = t1o1[r] + R[0][1][r] + R[1][1][r] + R[2][1][r] + R[3][1][r];
      }
      #pragma unroll
      for (int s = 3; s > 0; --s) { R[s][0] = R[s - 1][0]; R[s][1] = R[s - 1][1]; }
      R[0][0] = co0; R[0][1] = co1;
      const int rb = kq * 4;
      float* tpx = sT + w * 576 + l * 9;
      #pragma unroll
      for (int r = 0; r < 4; ++r) {
        sX[(w * 32 + rb + r) * 20 + r0]      = ppx0[r] + gho0[r];
        sX[(w * 32 + 16 + rb + r) * 20 + r0] = ppx1[r] + gho1[r];
        tpx[r] = tp0[r]; tpx[4 + r] = tp1[r];
      }
    }
    __syncthreads();

    // ---- tension_t reduce DISTRIBUTED across 4 waves (2 r-values each) ----
    {
      const int rf0 = w * 2;
      #pragma unroll
      for (int rr = 0; rr < 2; ++rr) {
        const int rf = rf0 + rr;
        float v = sT[l * 9 + rf] + sT[576 + l * 9 + rf]
                + sT[1152 + l * 9 + rf] + sT[1728 + l * 9 + rf] + b1a;
        float s = fmaxf(v, 0.f) * w2a;
        s += __shfl_xor(s, 1); s += __shfl_xor(s, 2);
        s += __shfl_xor(s, 4); s += __shfl_xor(s, 8);
        if (r0 == 0) {
          int row = (rf < 4) ? (kq * 4 + rf) : (16 + kq * 4 + (rf - 4));
          ast_f32(tensP + (((size_t)par * 8 + p) * 32 + q) * 32 + row, s);
        }
      }
    }

    // ---- pointwise LSTM core (no tension_t dependency) ----
    float hn_[2];
    #pragma unroll
    for (int e = 0; e < 2; ++e) {
      float gi = sX[(      b_loc) * 20 + c_loc + e] + bsv[0][e];
      float gf = sX[( 32 + b_loc) * 20 + c_loc + e] + bsv[1][e];
      float gg = sX[( 64 + b_loc) * 20 + c_loc + e] + bsv[2][e];
      float go = sX[( 96 + b_loc) * 20 + c_loc + e] + bsv[3][e];
      float c_new = sigf(gf) * cst[e] + sigf(gi) * tanh_(gg);
      cst[e] = c_new;
      hn_[e] = sigf(go) * tanh_(c_new);
    }
    float gzb = sGZ[par * 32 + b_loc];
    float hop[2] = { hnp[0] + gzb * hst[0], hnp[1] + gzb * hst[1] };  // h^out_{t-1}
    // h_new_t store
    {
      union { f16 h2[2]; unsigned u; } ph_;
      ph_.h2[0] = (f16)hn_[0]; ph_.h2[1] = (f16)hn_[1];
      ast_u32(hb[par] + (size_t)pb * 512 + c0 + c_loc, ph_.u);
    }
    post_wave(mySlot, (unsigned)(t + 1), l);   // per-wave: drain own vmem, lane0 store

    // ---- slack: deferred out write + speculative slot read + PGx(t+1) + x stage ----
    if (t >= 1) {
      f32x2 ov = {hop[0], hop[1]};
      *(f32x2*)(out + ((size_t)pb * 512 + (t - 1)) * 512 + c0 + c_loc) = ov;
    }
    hst[0] = hop[0]; hst[1] = hop[1];
    hnp[0] = hn_[0]; hnp[1] = hn_[1];
    // speculative read of the slot region for step t+1 (latency hides under PGx MFMA)
    spec0 = ald_u32(slotB + l);
    spec1 = ald_u32(slotB + 64 + l);
    if (t < 511) {
      char* sXcur = (((t + 1) & 1) ? sXt1 : sXt0);
      ppx0 = (f32x4){0,0,0,0}; ppx1 = (f32x4){0,0,0,0};
      #pragma unroll
      for (int ks = 0; ks < 8; ++ks) {
        const int cc = (((ks * 4 + kq) ^ (r0 & 7)) << 4);
        f16x8 a0 = *(const f16x8*)(sXcur + r0 * 512 + cc);
        f16x8 a1 = *(const f16x8*)(sXcur + (r0 + 16) * 512 + cc);
        MFMA16(a0, wbx[ks], ppx0); MFMA16(a1, wbx[ks], ppx1);
      }
      if (t < 510) {
        char* sXnxt = ((t & 1) ? sXt1 : sXt0);
        #pragma unroll
        for (int i = 0; i < 4; ++i) {
          const int U = i * 256 + tid;
          const int row = U >> 5, c = U & 31;
          const float* xp = x + ((size_t)(m0 + row) * 512 + (t + 2)) * 256 + c * 8;
          f32x4 xa = *(const f32x4*)xp;
          f32x4 xb_ = *(const f32x4*)(xp + 4);
          f16x8 xf;
          #pragma unroll
          for (int r = 0; r < 4; ++r) { xf[r] = (f16)xa[r]; xf[4 + r] = (f16)xb_[r]; }
          *(f16x8*)(sXnxt + row * 512 + ((c ^ (row & 7)) << 4)) = xf;
        }
      }
    }
  }

  // ---- epilogue: gz_511 -> h^out_511, h_n, c_n ----
  if (!__all((spec0 >= 512u) & (spec1 >= 512u)))
    poll_line128(slotB, 512u, l);
  {
    const float* tpb = tensP + ((size_t)(511 & 1) * 8 + p) * 1024;
    const int s8 = tid & 7;
    float acc = 0.f;
    #pragma unroll
    for (int j2 = 0; j2 < 4; ++j2)
      acc += ald_f32(tpb + (s8 * 4 + j2) * 32 + b_loc);
    acc += __shfl_xor(acc, 1); acc += __shfl_xor(acc, 2); acc += __shfl_xor(acc, 4);
    float tn = sigf(acc + bt2v);
    float rs = resb[511 * 256 + pb];
    float gzb = sigf(wg0 * rs + wg1 * tn + bgv) * zeta[511];
    float hop[2] = { hnp[0] + gzb * hst[0], hnp[1] + gzb * hst[1] };  // h^out_511
    f32x2 ov = {hop[0], hop[1]};
    *(f32x2*)(out + ((size_t)pb * 512 + 511) * 512 + c0 + c_loc) = ov;
    *(f32x2*)(out + 67108864 + (size_t)pb * 512 + c0 + c_loc) = ov;
    f32x2 cv2 = {cst[0], cst[1]};
    *(f32x2*)(out + 67108864 + 131072 + (size_t)pb * 512 + c0 + c_loc) = cv2;
  }
}

extern "C" void kernel_launch(void* const* d_in, const int* in_sizes, int n_in,
                              void* d_out, int out_size, void* d_ws, size_t ws_size,
                              hipStream_t stream) {
  (void)in_sizes; (void)n_in; (void)out_size; (void)ws_size;
  const float* x     = (const float*)d_in[0];
  const float* Wih   = (const float*)d_in[1];
  const float* Whh   = (const float*)d_in[2];
  const float* bih   = (const float*)d_in[3];
  const float* bhh   = (const float*)d_in[4];
  const float* Wproj = (const float*)d_in[5];
  const float* bproj = (const float*)d_in[6];
  const float* Wt1   = (const float*)d_in[7];
  const float* bt1   = (const float*)d_in[8];
  const float* Wt2   = (const float*)d_in[9];
  const float* bt2   = (const float*)d_in[10];
  const float* Wg    = (const float*)d_in[11];
  const float* bg    = (const float*)d_in[12];
  float* out = (float*)d_out;
  char* ws = (char*)d_ws;
  hipFuncSetAttribute((const void*)k_lstm, hipFuncAttributeMaxDynamicSharedMemorySize, 131072);
  k_init<<<dim3(1024), dim3(256), 0, stream>>>(x, Wih, Whh, bih, bhh, Wt1, ws);
  k_tables<<<dim3(512), dim3(256), 0, stream>>>(Wproj, bproj, ws);
  k_res<<<dim3(32768), dim3(256), 0, stream>>>(x, ws);
  k_lstm<<<dim3(NBLK), dim3(256), 85248, stream>>>(x, bt1, Wt2, bt2, Wg, bg, out, ws);
}

// Round 17
// 3233.856 us; speedup vs baseline: 1.2778x; 1.2778x over previous
//
#include <hip/hip_runtime.h>

typedef _Float16 f16;
typedef _Float16 f16x8 __attribute__((ext_vector_type(8)));
typedef float f32x4 __attribute__((ext_vector_type(4)));
typedef float f32x2 __attribute__((ext_vector_type(2)));
typedef unsigned long long u64;

#define DEVFN static __device__ __forceinline__

#define NBLK 256

// ---------------- workspace layout (bytes) ----------------
#define OFF_WCAT 0ULL                          // 2048*768*2 gates weights
#define OFF_WT1A (OFF_WCAT + 2048ULL*768*2)    // 512*512*2  (W1h + W1m/5)
#define OFF_WT1B (OFF_WT1A + 512ULL*512*2)     // 512*512*2  (W1m/5)
#define OFF_HB0  (OFF_WT1B + 512ULL*512*2)     // 256*512*2  h_new parity 0
#define OFF_HB1  (OFF_HB0  + 256ULL*512*2)     // 256*512*2  h_new parity 1
#define OFF_BSUM (OFF_HB1  + 256ULL*512*2)     // 2048*4
#define OFF_U    (OFF_BSUM + 2048ULL*4)
#define OFF_V    (OFF_U    + 512ULL*256*4)
#define OFF_CU   (OFF_V    + 512ULL*256*4)
#define OFF_CV   (OFF_CU   + 512ULL*4)
#define OFF_ZETA (OFF_CV   + 512ULL*4)
#define OFF_RES  (OFF_ZETA + 512ULL*4)         // 512*256*4
#define OFF_TENSP (OFF_RES + 512ULL*256*4)     // 2 par * 8 panel * 32 q * 32 b * 4B = 64KB
#define OFF_SLOT (OFF_TENSP + 16384ULL*4)      // 8 panels * 64 u32 (H line + spare)

__constant__ float CGAM[15] = {14.134725f, 21.02204f, 25.010858f, 30.424876f, 32.935062f,
  37.586178f, 40.91872f, 43.327073f, 48.005151f, 49.773832f, 52.970321f,
  56.446248f, 59.347044f, 60.831779f, 65.112544f};

DEVFN float sigf(float v) { return 1.f / (1.f + __expf(-v)); }
DEVFN float tanh_(float v) {
  v = fminf(fmaxf(v, -15.f), 15.f);
  float e = __expf(2.f * v);
  return (e - 1.f) / (e + 1.f);
}

// ---- fence-free LLC-coherent access helpers ----
DEVFN float ald_f32(const float* p) {
  unsigned v = __hip_atomic_load((const unsigned*)p, __ATOMIC_RELAXED, __HIP_MEMORY_SCOPE_AGENT);
  union { unsigned u; float f; } c; c.u = v; return c.f;
}
DEVFN void ast_f32(float* p, float v) {
  union { float f; unsigned u; } c; c.f = v;
  __hip_atomic_store((unsigned*)p, c.u, __ATOMIC_RELAXED, __HIP_MEMORY_SCOPE_AGENT);
}
DEVFN u64 ald_u64(const void* p) {
  return __hip_atomic_load((const u64*)p, __ATOMIC_RELAXED, __HIP_MEMORY_SCOPE_AGENT);
}
DEVFN void ast_u32(void* p, unsigned v) {
  __hip_atomic_store((unsigned*)p, v, __ATOMIC_RELAXED, __HIP_MEMORY_SCOPE_AGENT);
}

// producer: all waves drain own vmem, converge, one relaxed slot store
DEVFN void post(unsigned* slot, unsigned v) {
  asm volatile("s_waitcnt vmcnt(0)" ::: "memory");
  __syncthreads();
  if (threadIdx.x == 0)
    __hip_atomic_store(slot, v, __ATOMIC_RELAXED, __HIP_MEMORY_SCOPE_AGENT);
}
// consumer: PER-WAVE poll of the 128B slot line (no block convergence —
// each wave proceeds independently once IT has seen all 32 slots >= target)
DEVFN void wait_line(const unsigned* line, unsigned target) {
  const unsigned* pp = line + (threadIdx.x & 31);
  long sp = 0;
  for (;;) {
    unsigned v = __hip_atomic_load(pp, __ATOMIC_RELAXED, __HIP_MEMORY_SCOPE_AGENT);
    if (__all(v >= target)) break;
    __builtin_amdgcn_s_sleep(1);
    if (++sp > (1L << 21)) break;
  }
}

// ---------------- init ----------------
__global__ void k_init(const float* __restrict__ x, const float* __restrict__ Wih,
                       const float* __restrict__ Whh, const float* __restrict__ bih,
                       const float* __restrict__ bhh, const float* __restrict__ Wt1f,
                       char* __restrict__ ws) {
  f16* Wcat = (f16*)(ws + OFF_WCAT);
  f16* WhmA = (f16*)(ws + OFF_WT1A);
  f16* WmB  = (f16*)(ws + OFF_WT1B);
  f16* hb0  = (f16*)(ws + OFF_HB0);
  float* bsum = (float*)(ws + OFF_BSUM);
  float* tensP = (float*)(ws + OFF_TENSP);
  unsigned* slots = (unsigned*)(ws + OFF_SLOT);
  int gtid = blockIdx.x * blockDim.x + threadIdx.x;
  int nth = gridDim.x * blockDim.x;
  for (int i = gtid; i < 2048 * 768; i += nth) {
    int n = i / 768, k = i - n * 768;
    float w = (k < 256) ? Wih[n * 256 + k] : Whh[n * 512 + (k - 256)];
    Wcat[i] = (f16)w;
  }
  for (int i = gtid; i < 512 * 512; i += nth) {
    int n = i >> 9, k = i & 511;
    float wh = Wt1f[n * 1024 + k];
    float wm = Wt1f[n * 1024 + 512 + k] * 0.2f;
    WhmA[i] = (f16)(wh + wm);
    WmB[i]  = (f16)wm;
  }
  for (int i = gtid; i < 2048; i += nth) bsum[i] = bih[i] + bhh[i];
  for (int i = gtid; i < 256 * 512; i += nth) hb0[i] = (f16)0.f;
  for (int i = gtid; i < 16384; i += nth) tensP[i] = 0.f;
  for (int i = gtid; i < 8 * 64; i += nth) slots[i] = 0u;
}

// ---------------- per-t tables ----------------
__global__ void k_tables(const float* __restrict__ Wproj, const float* __restrict__ bproj,
                         char* __restrict__ ws) {
  float* u    = (float*)(ws + OFF_U);
  float* v    = (float*)(ws + OFF_V);
  float* cu   = (float*)(ws + OFF_CU);
  float* cv   = (float*)(ws + OFF_CV);
  float* zeta = (float*)(ws + OFF_ZETA);
  int t = blockIdx.x;
  int k = threadIdx.x;
  float tf = (float)t;
  float cg[15], sg[15], ph[15];
  #pragma unroll
  for (int m = 0; m < 15; ++m) {
    float ang = CGAM[m] * tf;
    cg[m] = cosf(ang);
    sg[m] = sinf(ang);
    ph[m] = (float)exp(-0.1 * (double)CGAM[m]);
  }
  float uu = 0.f, vv = 0.f;
  #pragma unroll
  for (int m = 0; m < 15; ++m) {
    uu += Wproj[m * 256 + k] * cg[m] * ph[m];
    vv += Wproj[(15 + m) * 256 + k] * sg[m] * ph[m];
  }
  u[t * 256 + k] = uu;
  v[t * 256 + k] = vv;
  if (k == 0) {
    float a = 0.f, b2 = 0.f, z = 0.f;
    #pragma unroll
    for (int m = 0; m < 15; ++m) {
      a  += bproj[m] * cg[m] * ph[m];
      b2 += bproj[15 + m] * sg[m] * ph[m];
      z  += ph[m] * cg[m];
    }
    cu[t] = a; cv[t] = b2; zeta[t] = z / 15.f;
  }
}

// ---------------- resonance precompute ----------------
__global__ void k_res(const float* __restrict__ x, char* __restrict__ ws) {
  const float* u  = (const float*)(ws + OFF_U);
  const float* v  = (const float*)(ws + OFF_V);
  const float* cu = (const float*)(ws + OFF_CU);
  const float* cv = (const float*)(ws + OFF_CV);
  float* resb     = (float*)(ws + OFF_RES);
  int wid = blockIdx.x * 4 + (threadIdx.x >> 6);
  int l = threadIdx.x & 63;
  int b = wid >> 9, t = wid & 511;
  const f32x4 xx = *(const f32x4*)(x + ((size_t)(b * 512 + t)) * 256 + l * 4);
  const f32x4 uu = *(const f32x4*)(u + t * 256 + l * 4);
  const f32x4 vv = *(const f32x4*)(v + t * 256 + l * 4);
  float cc = xx[0]*uu[0] + xx[1]*uu[1] + xx[2]*uu[2] + xx[3]*uu[3];
  float ss = xx[0]*vv[0] + xx[1]*vv[1] + xx[2]*vv[2] + xx[3]*vv[3];
  #pragma unroll
  for (int m = 1; m < 64; m <<= 1) { cc += __shfl_xor(cc, m); ss += __shfl_xor(ss, m); }
  if (l == 0) {
    cc += cu[t]; ss += cv[t];
    float r = sqrtf(cc * cc + ss * ss + 1e-8f) - 0.5f;
    resb[t * 256 + b] = sigf(r);
  }
}

#define MFMA16(qv, wv, av) av = __builtin_amdgcn_mfma_f32_16x16x32_f16(qv, wv, av, 0, 0, 0)

// ---------------- persistent fused recurrent kernel (256 blocks, uniform) ----------------
// Identity: h^out_t = h_new_t + gz_t*h^out_{t-1}  => fragment recurrences; only h_new is
// communicated; tensP_t stored mid-step, covered by the same end-of-step post.
// ONE cross-block hop per step; per-wave slot polling; stage loads issued before gz
// compute so LLC latency overlaps VALU work.
__global__ void __launch_bounds__(256, 1)
k_lstm(const float* __restrict__ x, const float* __restrict__ bt1,
       const float* __restrict__ wt2, const float* __restrict__ bt2,
       const float* __restrict__ wg, const float* __restrict__ bg,
       float* __restrict__ out, char* __restrict__ ws) {
  extern __shared__ char lds[];
  char*  sH   = lds;                        // 32 KB  h_new tile [32][512] f16 swizzled
  char*  sXt0 = lds + 32768;                // 16 KB  x tile buf0
  char*  sXt1 = lds + 49152;                // 16 KB  x tile buf1
  float* sT   = (float*)(lds + 65536);      // 9216 B tension exchange [4][64][9]
  float* sX   = (float*)(lds + 74752);      // 10 KB  gate exchange [4][32][20] f32
  float* sGZ  = (float*)(lds + 84992);      // 128 B  gz_{t-1}[32]

  const f16* __restrict__ Wcat = (const f16*)(ws + OFF_WCAT);
  const f16* __restrict__ WhmA = (const f16*)(ws + OFF_WT1A);
  const f16* __restrict__ WmB  = (const f16*)(ws + OFF_WT1B);
  f16* hb[2] = { (f16*)(ws + OFF_HB0), (f16*)(ws + OFF_HB1) };
  const float* bsum = (const float*)(ws + OFF_BSUM);
  const float* zeta = (const float*)(ws + OFF_ZETA);
  const float* resb = (const float*)(ws + OFF_RES);
  float* tensP = (float*)(ws + OFF_TENSP);
  unsigned* slots = (unsigned*)(ws + OFF_SLOT);

  const int tid = threadIdx.x;
  const int w = tid >> 6, l = tid & 63;
  const int r0 = l & 15, kq = l >> 4;
  const int bid = blockIdx.x;
  const int p = bid >> 5, q = bid & 31;
  const int c0 = q * 16, m0 = p * 32;

  unsigned* slotH = slots + p * 64;        // 128B line: 32 H slots
  unsigned* myH = slotH + q;

  // ---- persistent weight fragments (registers) ----
  f16x8 wbh[16], wbx[8];
  {
    const f16* Wr = Wcat + (size_t)(w * 512 + c0 + r0) * 768 + kq * 8;
    #pragma unroll
    for (int ks = 0; ks < 16; ++ks) wbh[ks] = *(const f16x8*)(Wr + 256 + ks * 32);
    #pragma unroll
    for (int ks = 0; ks < 8; ++ks)  wbx[ks] = *(const f16x8*)(Wr + ks * 32);
  }
  f16x8 wbhm[4], wbm[4];   // tension weights, K-split: wave w owns k in [w*128, w*128+128)
  {
    const f16* Wa = WhmA + (size_t)(q * 16 + r0) * 512 + w * 128 + kq * 8;
    const f16* Wb = WmB  + (size_t)(q * 16 + r0) * 512 + w * 128 + kq * 8;
    #pragma unroll
    for (int ks = 0; ks < 4; ++ks) {
      wbhm[ks] = *(const f16x8*)(Wa + ks * 32);
      wbm[ks]  = *(const f16x8*)(Wb + ks * 32);
    }
  }
  const float b1a = bt1[q * 16 + r0], w2a = wt2[q * 16 + r0];

  // ---- per-thread pointwise state: batch b_loc, cols c0+c_loc, +1 ----
  const int b_loc = tid >> 3, c_loc = (tid & 7) * 2;
  const int pb = m0 + b_loc;
  float bsv[4][2];
  #pragma unroll
  for (int g = 0; g < 4; ++g) {
    bsv[g][0] = bsum[g * 512 + c0 + c_loc];
    bsv[g][1] = bsum[g * 512 + c0 + c_loc + 1];
  }
  const float wg0 = wg[0], wg1 = wg[1], bt2v = bt2[0], bgv = bg[0];
  float cst[2] = {0.f, 0.f};       // c_t
  float hst[2] = {0.f, 0.f};       // h^out_{t-2}
  float hnp[2] = {0.f, 0.f};       // h_new_{t-1}

  // fragment recurrences
  f32x4 gho0 = {0,0,0,0}, gho1 = {0,0,0,0};   // Wh@h^out_{t-1}
  f32x4 t1o0 = {0,0,0,0}, t1o1 = {0,0,0,0};   // Whm@h^out_{t-1} (K-slice)
  f32x4 R[4][2];                               // C^out ring
  #pragma unroll
  for (int s = 0; s < 4; ++s) { R[s][0] = (f32x4){0,0,0,0}; R[s][1] = (f32x4){0,0,0,0}; }

  // ---- prologue: stage x_0 -> sXt0, PGx(0); stage x_1 -> sXt1 ----
  f32x4 ppx0 = {0,0,0,0}, ppx1 = {0,0,0,0};
  {
    #pragma unroll
    for (int i = 0; i < 4; ++i) {
      const int U = i * 256 + tid;
      const int row = U >> 5, c = U & 31;
      const float* xp = x + ((size_t)(m0 + row) * 512 + 0) * 256 + c * 8;
      f32x4 xa = *(const f32x4*)xp;
      f32x4 xb_ = *(const f32x4*)(xp + 4);
      f16x8 xf;
      #pragma unroll
      for (int r = 0; r < 4; ++r) { xf[r] = (f16)xa[r]; xf[4 + r] = (f16)xb_[r]; }
      *(f16x8*)(sXt0 + row * 512 + ((c ^ (row & 7)) << 4)) = xf;
    }
    __syncthreads();
    #pragma unroll
    for (int ks = 0; ks < 8; ++ks) {
      const int cc = (((ks * 4 + kq) ^ (r0 & 7)) << 4);
      f16x8 a0 = *(const f16x8*)(sXt0 + r0 * 512 + cc);
      f16x8 a1 = *(const f16x8*)(sXt0 + (r0 + 16) * 512 + cc);
      MFMA16(a0, wbx[ks], ppx0); MFMA16(a1, wbx[ks], ppx1);
    }
    #pragma unroll
    for (int i = 0; i < 4; ++i) {
      const int U = i * 256 + tid;
      const int row = U >> 5, c = U & 31;
      const float* xp = x + ((size_t)(m0 + row) * 512 + 1) * 256 + c * 8;
      f32x4 xa = *(const f32x4*)xp;
      f32x4 xb_ = *(const f32x4*)(xp + 4);
      f16x8 xf;
      #pragma unroll
      for (int r = 0; r < 4; ++r) { xf[r] = (f16)xa[r]; xf[4 + r] = (f16)xb_[r]; }
      *(f16x8*)(sXt1 + row * 512 + ((c ^ (row & 7)) << 4)) = xf;
    }
    __syncthreads();
  }

  for (int t = 0; t < 512; ++t) {
    const int par = t & 1, parm = (t - 1) & 1;

    wait_line(slotH, (unsigned)t);            // per-wave; h_new_{t-1}+tensP_{t-1} visible

    // ---- issue h stage loads FIRST (latency overlaps gz compute below) ----
    u64 lo[8], hi[8];
    if (t > 0) {
      const f16* hsrc = hb[parm];
      #pragma unroll
      for (int i = 0; i < 8; ++i) {
        const int B = i * 256 + tid;
        const int row = B >> 6, c = B & 63;
        const u64* pp = (const u64*)(hsrc + (size_t)(m0 + row) * 512 + c * 8);
        lo[i] = ald_u64(pp); hi[i] = ald_u64(pp + 1);
      }
    }

    // ---- gz_{t-1} (VALU + 4 LLC reads, overlapped with the loads above) ----
    {
      float tn = 0.f;
      if (t >= 3) {
        const float* tpb = tensP + ((size_t)parm * 8 + p) * 1024;   // [q][32]
        const int s8 = tid & 7;
        float acc = 0.f;
        #pragma unroll
        for (int j2 = 0; j2 < 4; ++j2)
          acc += ald_f32(tpb + (s8 * 4 + j2) * 32 + b_loc);
        acc += __shfl_xor(acc, 1); acc += __shfl_xor(acc, 2); acc += __shfl_xor(acc, 4);
        tn = sigf(acc + bt2v);
      }
      float g = 0.f;
      if (t >= 1) {
        float rs = resb[(t - 1) * 256 + pb];
        g = sigf(wg0 * rs + wg1 * tn + bgv) * zeta[t - 1];
      }
      if ((tid & 7) == 0) sGZ[b_loc] = g;
    }

    // ---- LDS writes of the staged h tile ----
    if (t > 0) {
      #pragma unroll
      for (int i = 0; i < 8; ++i) {
        const int B = i * 256 + tid;
        const int row = B >> 6, c = B & 63;
        union { u64 qq[2]; uint4 v4; } uq; uq.qq[0] = lo[i]; uq.qq[1] = hi[i];
        *(uint4*)(sH + row * 1024 + ((c ^ (row & 7)) << 4)) = uq.v4;
      }
    }
    __syncthreads();

    // ---- GEMMs on h_new_{t-1} ----
    f32x4 ghn0 = {0,0,0,0}, ghn1 = {0,0,0,0};
    f32x4 t1n0 = {0,0,0,0}, t1n1 = {0,0,0,0};
    f32x4 cnw0 = {0,0,0,0}, cnw1 = {0,0,0,0};
    if (t > 0) {
      #pragma unroll
      for (int ks = 0; ks < 16; ++ks) {
        const int cc = (((ks * 4 + kq) ^ (r0 & 7)) << 4);
        f16x8 q0 = *(const f16x8*)(sH + r0 * 1024 + cc);
        f16x8 q1 = *(const f16x8*)(sH + (r0 + 16) * 1024 + cc);
        MFMA16(q0, wbh[ks], ghn0); MFMA16(q1, wbh[ks], ghn1);
      }
      #pragma unroll
      for (int ks = 0; ks < 4; ++ks) {
        const int cc = ((((w * 4 + ks) * 4 + kq) ^ (r0 & 7)) << 4);
        f16x8 q0 = *(const f16x8*)(sH + r0 * 1024 + cc);
        f16x8 q1 = *(const f16x8*)(sH + (r0 + 16) * 1024 + cc);
        MFMA16(q0, wbhm[ks], t1n0); MFMA16(q1, wbhm[ks], t1n1);
        MFMA16(q0, wbm[ks],  cnw0); MFMA16(q1, wbm[ks],  cnw1);
      }
    }

    // ---- fragment recurrences (gz_{t-1} from sGZ) + exchanges ----
    {
      float gz0[4], gz1[4];
      #pragma unroll
      for (int r = 0; r < 4; ++r) { gz0[r] = sGZ[kq * 4 + r]; gz1[r] = sGZ[16 + kq * 4 + r]; }
      f32x4 co0, co1, tp0, tp1;
      #pragma unroll
      for (int r = 0; r < 4; ++r) {
        gho0[r] = ghn0[r] + gz0[r] * gho0[r];
        gho1[r] = ghn1[r] + gz1[r] * gho1[r];
        t1o0[r] = t1n0[r] + gz0[r] * t1o0[r];
        t1o1[r] = t1n1[r] + gz1[r] * t1o1[r];
        co0[r] = cnw0[r] + gz0[r] * R[0][0][r];
        co1[r] = cnw1[r] + gz1[r] * R[0][1][r];
        tp0[r] = t1o0[r] + R[0][0][r] + R[1][0][r] + R[2][0][r] + R[3][0][r];
        tp1[r] = t1o1[r] + R[0][1][r] + R[1][1][r] + R[2][1][r] + R[3][1][r];
      }
      #pragma unroll
      for (int s = 3; s > 0; --s) { R[s][0] = R[s - 1][0]; R[s][1] = R[s - 1][1]; }
      R[0][0] = co0; R[0][1] = co1;
      const int rb = kq * 4;
      float* tpx = sT + w * 576 + l * 9;
      #pragma unroll
      for (int r = 0; r < 4; ++r) {
        sX[(w * 32 + rb + r) * 20 + r0]      = ppx0[r] + gho0[r];
        sX[(w * 32 + 16 + rb + r) * 20 + r0] = ppx1[r] + gho1[r];
        tpx[r] = tp0[r]; tpx[4 + r] = tp1[r];
      }
    }
    __syncthreads();

    // ---- tension_t reduce DISTRIBUTED across 4 waves (2 r-values each) ----
    {
      const int rf0 = w * 2;
      #pragma unroll
      for (int rr = 0; rr < 2; ++rr) {
        const int rf = rf0 + rr;
        float v = sT[l * 9 + rf] + sT[576 + l * 9 + rf]
                + sT[1152 + l * 9 + rf] + sT[1728 + l * 9 + rf] + b1a;
        float s = fmaxf(v, 0.f) * w2a;
        s += __shfl_xor(s, 1); s += __shfl_xor(s, 2);
        s += __shfl_xor(s, 4); s += __shfl_xor(s, 8);
        if (r0 == 0) {
          int row = (rf < 4) ? (kq * 4 + rf) : (16 + kq * 4 + (rf - 4));
          ast_f32(tensP + (((size_t)par * 8 + p) * 32 + q) * 32 + row, s);
        }
      }
    }

    // ---- pointwise LSTM core (no tension_t dependency) ----
    float hn_[2];
    #pragma unroll
    for (int e = 0; e < 2; ++e) {
      float gi = sX[(      b_loc) * 20 + c_loc + e] + bsv[0][e];
      float gf = sX[( 32 + b_loc) * 20 + c_loc + e] + bsv[1][e];
      float gg = sX[( 64 + b_loc) * 20 + c_loc + e] + bsv[2][e];
      float go = sX[( 96 + b_loc) * 20 + c_loc + e] + bsv[3][e];
      float c_new = sigf(gf) * cst[e] + sigf(gi) * tanh_(gg);
      cst[e] = c_new;
      hn_[e] = sigf(go) * tanh_(c_new);
    }
    float gzb = sGZ[b_loc];
    float hop[2] = { hnp[0] + gzb * hst[0], hnp[1] + gzb * hst[1] };  // h^out_{t-1}
    // h_new_t store
    {
      union { f16 h2[2]; unsigned u; } ph_;
      ph_.h2[0] = (f16)hn_[0]; ph_.h2[1] = (f16)hn_[1];
      ast_u32(hb[par] + (size_t)pb * 512 + c0 + c_loc, ph_.u);
    }
    post(myH, (unsigned)(t + 1));   // single hop: covers h_new_t AND tensP_t

    // ---- slack: deferred out write + PGx(t+1) + x_{t+2} direct stage ----
    if (t >= 1) {
      f32x2 ov = {hop[0], hop[1]};
      *(f32x2*)(out + ((size_t)pb * 512 + (t - 1)) * 512 + c0 + c_loc) = ov;
    }
    hst[0] = hop[0]; hst[1] = hop[1];
    hnp[0] = hn_[0]; hnp[1] = hn_[1];
    if (t < 511) {
      char* sXcur = (((t + 1) & 1) ? sXt1 : sXt0);
      ppx0 = (f32x4){0,0,0,0}; ppx1 = (f32x4){0,0,0,0};
      #pragma unroll
      for (int ks = 0; ks < 8; ++ks) {
        const int cc = (((ks * 4 + kq) ^ (r0 & 7)) << 4);
        f16x8 a0 = *(const f16x8*)(sXcur + r0 * 512 + cc);
        f16x8 a1 = *(const f16x8*)(sXcur + (r0 + 16) * 512 + cc);
        MFMA16(a0, wbx[ks], ppx0); MFMA16(a1, wbx[ks], ppx1);
      }
      if (t < 510) {
        char* sXnxt = ((t & 1) ? sXt1 : sXt0);
        #pragma unroll
        for (int i = 0; i < 4; ++i) {
          const int U = i * 256 + tid;
          const int row = U >> 5, c = U & 31;
          const float* xp = x + ((size_t)(m0 + row) * 512 + (t + 2)) * 256 + c * 8;
          f32x4 xa = *(const f32x4*)xp;
          f32x4 xb_ = *(const f32x4*)(xp + 4);
          f16x8 xf;
          #pragma unroll
          for (int r = 0; r < 4; ++r) { xf[r] = (f16)xa[r]; xf[4 + r] = (f16)xb_[r]; }
          *(f16x8*)(sXnxt + row * 512 + ((c ^ (row & 7)) << 4)) = xf;
        }
      }
    }
  }

  // ---- epilogue: gz_511 -> h^out_511, h_n, c_n ----
  wait_line(slotH, 512u);
  {
    const float* tpb = tensP + ((size_t)(511 & 1) * 8 + p) * 1024;
    const int s8 = tid & 7;
    float acc = 0.f;
    #pragma unroll
    for (int j2 = 0; j2 < 4; ++j2)
      acc += ald_f32(tpb + (s8 * 4 + j2) * 32 + b_loc);
    acc += __shfl_xor(acc, 1); acc += __shfl_xor(acc, 2); acc += __shfl_xor(acc, 4);
    float tn = sigf(acc + bt2v);
    float rs = resb[511 * 256 + pb];
    float gzb = sigf(wg0 * rs + wg1 * tn + bgv) * zeta[511];
    float hop[2] = { hnp[0] + gzb * hst[0], hnp[1] + gzb * hst[1] };  // h^out_511
    f32x2 ov = {hop[0], hop[1]};
    *(f32x2*)(out + ((size_t)pb * 512 + 511) * 512 + c0 + c_loc) = ov;
    *(f32x2*)(out + 67108864 + (size_t)pb * 512 + c0 + c_loc) = ov;
    f32x2 cv2 = {cst[0], cst[1]};
    *(f32x2*)(out + 67108864 + 131072 + (size_t)pb * 512 + c0 + c_loc) = cv2;
  }
}

extern "C" void kernel_launch(void* const* d_in, const int* in_sizes, int n_in,
                              void* d_out, int out_size, void* d_ws, size_t ws_size,
                              hipStream_t stream) {
  (void)in_sizes; (void)n_in; (void)out_size; (void)ws_size;
  const float* x     = (const float*)d_in[0];
  const float* Wih   = (const float*)d_in[1];
  const float* Whh   = (const float*)d_in[2];
  const float* bih   = (const float*)d_in[3];
  const float* bhh   = (const float*)d_in[4];
  const float* Wproj = (const float*)d_in[5];
  const float* bproj = (const float*)d_in[6];
  const float* Wt1   = (const float*)d_in[7];
  const float* bt1   = (const float*)d_in[8];
  const float* Wt2   = (const float*)d_in[9];
  const float* bt2   = (const float*)d_in[10];
  const float* Wg    = (const float*)d_in[11];
  const float* bg    = (const float*)d_in[12];
  float* out = (float*)d_out;
  char* ws = (char*)d_ws;
  hipFuncSetAttribute((const void*)k_lstm, hipFuncAttributeMaxDynamicSharedMemorySize, 131072);
  k_init<<<dim3(1024), dim3(256), 0, stream>>>(x, Wih, Whh, bih, bhh, Wt1, ws);
  k_tables<<<dim3(512), dim3(256), 0, stream>>>(Wproj, bproj, ws);
  k_res<<<dim3(32768), dim3(256), 0, stream>>>(x, ws);
  k_lstm<<<dim3(NBLK), dim3(256), 85120, stream>>>(x, bt1, Wt2, bt2, Wg, bg, out, ws);
}